// Round 5
// baseline (162.189 us; speedup 1.0000x reference)
//
#include <hip/hip_runtime.h>

// Self-attention (SAGAN-style), B=16, C=64, H=W=64. d8=8, d2=32, N=4096, M=1024.
// Round 5: fix score-MFMA B-fragment addressing. The B operand of
// mfma_16x16x32 takes k = quad*8+j from each lane quad; the round-3/4 code
// read the same 16B (cols 0..7) for ALL quads, so k-pad zeros were never
// consumed and S came out exactly 4x too large (sharpened softmax, absmax
// 0.199 both rounds, deterministic). Fix: "+ quad*8" in the 4 score loads.
// Structure otherwise unchanged: scores AND PV on bf16 MFMA, per-wave-private
// P buffer, double-buffered chunk staging, 1 barrier per chunk.

#define B_   16
#define C_   64
#define HW_  4096
#define M_   1024

typedef __attribute__((ext_vector_type(8))) short bf16x8;
typedef __attribute__((ext_vector_type(4))) float f32x4;

__device__ __forceinline__ unsigned short f2bf(float f) {   // RNE
    union { float f; unsigned int u; } v; v.f = f;
    return (unsigned short)((v.u + 0x7FFFu + ((v.u >> 16) & 1u)) >> 16);
}
__device__ __forceinline__ unsigned int pack2(float a, float b) {
    return (unsigned int)f2bf(a) | ((unsigned int)f2bf(b) << 16);
}

// ---------------------------------------------------------------------------
// proj: thetaB(B,N,8) bf16, phiB(B,1024,8) bf16, gT(B,32,1024) bf16
// block = 256 thr over 128 px (2 rows); half 0: theta+phi+g0..7, half 1: g8..31.
// ---------------------------------------------------------------------------
__global__ __launch_bounds__(256) void proj_kernel(
    const float* __restrict__ x,
    const float* __restrict__ w_theta, const float* __restrict__ b_theta,
    const float* __restrict__ w_phi,   const float* __restrict__ b_phi,
    const float* __restrict__ w_g,     const float* __restrict__ b_g,
    unsigned short* __restrict__ thetaB,
    unsigned short* __restrict__ phiB,
    unsigned short* __restrict__ gT)
{
    __shared__ float pool_l[128][41];    // slots: 0..7 phi, 8..39 g
    const int tid  = threadIdx.x;
    const int b    = blockIdx.y;
    const int rp   = blockIdx.x;         // row pair 0..31
    const int n0   = rp * 128;
    const int px   = tid & 127;
    const int half = tid >> 7;           // wave-uniform

    const float* xp = x + (size_t)b * C_ * HW_ + n0 + px;

    if (half == 0) {
        float th[8], ph[8], g0[8];
        #pragma unroll
        for (int o = 0; o < 8; o++) { th[o] = b_theta[o]; ph[o] = b_phi[o]; g0[o] = b_g[o]; }
        for (int cg = 0; cg < 4; cg++) {
            float xv[16];
            #pragma unroll
            for (int i = 0; i < 16; i++) xv[i] = xp[(size_t)(cg * 16 + i) * HW_];
            #pragma unroll
            for (int i = 0; i < 16; i++) {
                const int c = cg * 16 + i; const float v = xv[i];
                #pragma unroll
                for (int o = 0; o < 8; o++) th[o] += v * w_theta[o * 64 + c];
                #pragma unroll
                for (int o = 0; o < 8; o++) ph[o] += v * w_phi[o * 64 + c];
                #pragma unroll
                for (int o = 0; o < 8; o++) g0[o] += v * w_g[o * 64 + c];
            }
        }
        unsigned short* tout = thetaB + ((size_t)b * HW_ + n0 + px) * 8;
        uint4 tv;
        tv.x = pack2(th[0], th[1]); tv.y = pack2(th[2], th[3]);
        tv.z = pack2(th[4], th[5]); tv.w = pack2(th[6], th[7]);
        *(uint4*)tout = tv;
        #pragma unroll
        for (int o = 0; o < 8; o++) { pool_l[px][o] = ph[o]; pool_l[px][8 + o] = g0[o]; }
    } else {
        float gg[24];
        #pragma unroll
        for (int o = 0; o < 24; o++) gg[o] = b_g[8 + o];
        for (int cg = 0; cg < 4; cg++) {
            float xv[16];
            #pragma unroll
            for (int i = 0; i < 16; i++) xv[i] = xp[(size_t)(cg * 16 + i) * HW_];
            #pragma unroll
            for (int i = 0; i < 16; i++) {
                const int c = cg * 16 + i; const float v = xv[i];
                #pragma unroll
                for (int o = 0; o < 24; o++) gg[o] += v * w_g[(8 + o) * 64 + c];
            }
        }
        #pragma unroll
        for (int o = 0; o < 24; o++) pool_l[px][16 + o] = gg[o];
    }
    __syncthreads();

    // 2x2 max-pool: pooled row rp, pooled cols 0..31
    if (tid < 32) {
        const int pc  = tid;
        const int p00 = 2 * pc, p01 = 2 * pc + 1, p10 = 64 + 2 * pc, p11 = 65 + 2 * pc;
        const int mq  = rp * 32 + pc;
        float o8[8];
        #pragma unroll
        for (int o = 0; o < 8; o++)
            o8[o] = fmaxf(fmaxf(pool_l[p00][o], pool_l[p01][o]),
                          fmaxf(pool_l[p10][o], pool_l[p11][o]));
        unsigned short* pout = phiB + ((size_t)b * M_ + mq) * 8;
        uint4 pv;
        pv.x = pack2(o8[0], o8[1]); pv.y = pack2(o8[2], o8[3]);
        pv.z = pack2(o8[4], o8[5]); pv.w = pack2(o8[6], o8[7]);
        *(uint4*)pout = pv;
    } else if (tid < 64) {
        const int j   = tid - 32;
        const int p00 = 2 * j, p01 = 2 * j + 1, p10 = 64 + 2 * j, p11 = 65 + 2 * j;
        unsigned short* gout = gT + (size_t)b * 32 * M_ + rp * 32 + j;
        #pragma unroll
        for (int c = 0; c < 32; c++) {
            const int s = c + 8;
            float v = fmaxf(fmaxf(pool_l[p00][s], pool_l[p01][s]),
                            fmaxf(pool_l[p10][s], pool_l[p11][s]));
            gout[(size_t)c * M_] = f2bf(v);
        }
    }
}

// ---------------------------------------------------------------------------
// attn: block = (batch, 64-q tile), 256 thr = 4 waves. Wave wv owns q rows
// wv*16..+15. Per 64-m chunk: 4 score MFMAs (k zero-padded 8->32) -> exp ->
// bf16 P in per-wave LDS -> 2x2 PV MFMAs. Double-buffered staging, 1 barrier.
// ---------------------------------------------------------------------------
__global__ __launch_bounds__(256) void attn_kernel(
    const float* __restrict__ x,
    const unsigned short* __restrict__ thetaB,
    const unsigned short* __restrict__ phiB,
    const unsigned short* __restrict__ gTg,
    const float* __restrict__ w_o, const float* __restrict__ b_o,
    const float* __restrict__ sigma,
    float* __restrict__ out)
{
    __shared__ __align__(16) unsigned short pbuf[2][64 * 32];  // [m][k0..31], k>=8 zero
    __shared__ __align__(16) unsigned short gbuf[2][32 * 72];  // [c][m], stride 72
    __shared__ __align__(16) unsigned short P_buf[4][16 * 72]; // per-wave [qloc][m]
    __shared__ float O_l[64 * 33];
    __shared__ float rs_l[64];

    const int tid   = threadIdx.x;
    const int b     = blockIdx.y;
    const int qbase = blockIdx.x * 64;
    const int lane  = tid & 63;
    const int wv    = tid >> 6;
    const int ln15  = lane & 15;
    const int quad  = lane >> 4;

    // zero-fill BOTH pbuf buffers (8192 B = 512 uint4); staging rewrites
    // cols 0..7 only, score MFMA quads 1..3 read the zero pads.
    ((uint4*)pbuf)[tid]       = make_uint4(0, 0, 0, 0);
    ((uint4*)pbuf)[tid + 256] = make_uint4(0, 0, 0, 0);

    // theta A-fragment: lane q = wv*16+ln15 reads its 16B row for all quads
    // (quads 1-3 hold repeated theta k=0..7; B k>=8 is exact 0 -> no effect)
    bf16x8 afrag;
    {
        const unsigned short* tp = thetaB + ((size_t)b * HW_ + qbase + wv * 16 + ln15) * 8;
        afrag = *(const bf16x8*)tp;
    }

    const int sc  = tid >> 3;   // 0..31: c row for gT staging
    const int seg = tid & 7;

    f32x4 acc0 = {0.f, 0.f, 0.f, 0.f};
    f32x4 acc1 = {0.f, 0.f, 0.f, 0.f};
    float rs_acc[4] = {0.f, 0.f, 0.f, 0.f};

    __syncthreads();   // pbuf zero-fill visible

    // stage chunk 0 into buffer 0
    {
        uint4 v = *(const uint4*)(gTg + (((size_t)b * 32 + sc) << 10) + seg * 8);
        *(uint4*)&gbuf[0][sc * 72 + seg * 8] = v;
        if (tid < 64) {
            uint4 p = *(const uint4*)(phiB + ((size_t)b * M_ + tid) * 8);
            *(uint4*)&pbuf[0][tid * 32] = p;
        }
    }

    for (int ch = 0; ch < 16; ch++) {
        __syncthreads();   // staged buf[ch&1] visible; buf[(ch+1)&1] free
        const int bi = ch & 1;
        if (ch < 15) {
            const int m0 = (ch + 1) * 64;
            uint4 v = *(const uint4*)(gTg + (((size_t)b * 32 + sc) << 10) + m0 + seg * 8);
            *(uint4*)&gbuf[bi ^ 1][sc * 72 + seg * 8] = v;
            if (tid < 64) {
                uint4 p = *(const uint4*)(phiB + ((size_t)b * M_ + m0 + tid) * 8);
                *(uint4*)&pbuf[bi ^ 1][tid * 32] = p;
            }
        }

        // ---- scores: S[16q x 64m] = theta . phi  (4 MFMAs, k-padded).
        // B-fragment: quad selects its k-slice -> "+ quad*8" is REQUIRED so
        // quads 1..3 read the zero pad (round-3/4 bug: missing -> S = 4*S).
        const f32x4 zc = {0.f, 0.f, 0.f, 0.f};
        f32x4 s0 = __builtin_amdgcn_mfma_f32_16x16x32_bf16(
            afrag, *(const bf16x8*)&pbuf[bi][(0 * 16 + ln15) * 32 + quad * 8], zc, 0, 0, 0);
        f32x4 s1 = __builtin_amdgcn_mfma_f32_16x16x32_bf16(
            afrag, *(const bf16x8*)&pbuf[bi][(1 * 16 + ln15) * 32 + quad * 8], zc, 0, 0, 0);
        f32x4 s2 = __builtin_amdgcn_mfma_f32_16x16x32_bf16(
            afrag, *(const bf16x8*)&pbuf[bi][(2 * 16 + ln15) * 32 + quad * 8], zc, 0, 0, 0);
        f32x4 s3 = __builtin_amdgcn_mfma_f32_16x16x32_bf16(
            afrag, *(const bf16x8*)&pbuf[bi][(3 * 16 + ln15) * 32 + quad * 8], zc, 0, 0, 0);

        // ---- exp + rowsum partials + RNE-bf16 P (per-wave private)
        #pragma unroll
        for (int t = 0; t < 4; t++) {
            f32x4 sv = (t == 0) ? s0 : (t == 1) ? s1 : (t == 2) ? s2 : s3;
            #pragma unroll
            for (int r = 0; r < 4; r++) {
                float p = __expf(fminf(sv[r], 80.f));
                rs_acc[r] += p;
                P_buf[wv][(quad * 4 + r) * 72 + t * 16 + ln15] = f2bf(p);
            }
        }

        // ---- PV: O[16q x 32c] += P . g^T  (wave-local P, no barrier needed)
        #pragma unroll
        for (int s_ = 0; s_ < 2; s_++) {
            bf16x8 pa  = *(const bf16x8*)&P_buf[wv][ln15 * 72 + s_ * 32 + quad * 8];
            bf16x8 gb0 = *(const bf16x8*)&gbuf[bi][ln15 * 72 + s_ * 32 + quad * 8];
            bf16x8 gb1 = *(const bf16x8*)&gbuf[bi][(16 + ln15) * 72 + s_ * 32 + quad * 8];
            acc0 = __builtin_amdgcn_mfma_f32_16x16x32_bf16(pa, gb0, acc0, 0, 0, 0);
            acc1 = __builtin_amdgcn_mfma_f32_16x16x32_bf16(pa, gb1, acc1, 0, 0, 0);
        }
    }

    // rowsum: reduce partials across the 16 ln15 lanes (columns of S)
    #pragma unroll
    for (int r = 0; r < 4; r++) {
        float v = rs_acc[r];
        v += __shfl_xor(v, 1); v += __shfl_xor(v, 2);
        v += __shfl_xor(v, 4); v += __shfl_xor(v, 8);
        if (ln15 == 0) rs_l[wv * 16 + quad * 4 + r] = v;
    }
    // O to LDS (C-layout: col=ln15, row=quad*4+reg)
    {
        const int qb0 = wv * 16 + quad * 4;
        #pragma unroll
        for (int r = 0; r < 4; r++) {
            O_l[(qb0 + r) * 33 + ln15]      = acc0[r];
            O_l[(qb0 + r) * 33 + 16 + ln15] = acc1[r];
        }
    }
    __syncthreads();

    // epilogue: normalize + w_o conv + bias + residual
    const int q = tid & 63;
    const float rowsum = rs_l[q];
    const float sg  = sigma[0];
    const float inv = sg / rowsum;
    float o[32];
    #pragma unroll
    for (int c = 0; c < 32; c++) o[c] = O_l[q * 33 + c];
    const size_t xb = (size_t)b * C_ * HW_ + qbase + q;
    #pragma unroll
    for (int k = 0; k < 16; k++) {
        const int co = wv * 16 + k;
        float t = 0.f;
        #pragma unroll
        for (int c = 0; c < 32; c++) t += w_o[co * 32 + c] * o[c];
        out[xb + (size_t)co * HW_] = x[xb + (size_t)co * HW_] + t * inv + sg * b_o[co];
    }
}

// ---------------------------------------------------------------------------
extern "C" void kernel_launch(void* const* d_in, const int* in_sizes, int n_in,
                              void* d_out, int out_size, void* d_ws, size_t ws_size,
                              hipStream_t stream)
{
    const float* x       = (const float*)d_in[0];
    const float* w_theta = (const float*)d_in[1];
    const float* b_theta = (const float*)d_in[2];
    const float* w_phi   = (const float*)d_in[3];
    const float* b_phi   = (const float*)d_in[4];
    const float* w_g     = (const float*)d_in[5];
    const float* b_g     = (const float*)d_in[6];
    const float* w_o     = (const float*)d_in[7];
    const float* b_o     = (const float*)d_in[8];
    const float* sigma   = (const float*)d_in[9];
    float* out = (float*)d_out;

    // workspace (bf16): theta 1 MB, phi 0.25 MB, gT 1 MB
    unsigned short* thetaB = (unsigned short*)d_ws;
    unsigned short* phiB   = thetaB + (size_t)B_ * HW_ * 8;
    unsigned short* gT     = phiB + (size_t)B_ * M_ * 8;

    proj_kernel<<<dim3(32, B_), 256, 0, stream>>>(
        x, w_theta, b_theta, w_phi, b_phi, w_g, b_g, thetaB, phiB, gT);
    attn_kernel<<<dim3(64, B_), 256, 0, stream>>>(
        x, thetaB, phiB, gT, w_o, b_o, sigma, out);
}

// Round 6
// 159.299 us; speedup vs baseline: 1.0181x; 1.0181x over previous
//
#include <hip/hip_runtime.h>

// Self-attention (SAGAN-style), B=16, C=64, H=W=64. d8=8, d2=32, N=4096, M=1024.
// Round 6: LDS-free attention main loop. Operand swap: S^T = phi . theta^T so
// the exp'd scores sit in each lane exactly where the PV MFMA's B-fragment
// wants them (k = quad*8+j maps to m = sub*32 + (j>>2)*16 + quad*4 + (j&3)).
// P stays in registers; no ds_read/ds_write/barrier in the chunk loop.
// phi stored zero-padded [m][32] (k-pad read from memory = free masking);
// theta compact [n][8] masked once; gT stored PERMUTED so PV A-frag is one
// b128 per (sub, c-half). proj back to round-2 LDS x-tile staging.

#define B_   16
#define C_   64
#define HW_  4096
#define M_   1024

typedef __attribute__((ext_vector_type(8))) short bf16x8;
typedef __attribute__((ext_vector_type(4))) float f32x4;

__device__ __forceinline__ unsigned short f2bf(float f) {   // RNE
    union { float f; unsigned int u; } v; v.f = f;
    return (unsigned short)((v.u + 0x7FFFu + ((v.u >> 16) & 1u)) >> 16);
}
__device__ __forceinline__ unsigned int pack2(float a, float b) {
    return (unsigned int)f2bf(a) | ((unsigned int)f2bf(b) << 16);
}

// ---------------------------------------------------------------------------
// proj: thetaB(B,N,8) bf16 compact; phiB32(B,1024,32) bf16 with cols 8..31=0;
// gTp(B,32,1024) bf16 with m permuted per 32-block: for m, ms=m&31,
// p = (m&~31) + ((ms>>2)&3)*8 + (ms>>4)*4 + (ms&3).
// block = 256 thr, x tile 64c x 128px staged via float4 (round-2 structure).
// ---------------------------------------------------------------------------
__global__ __launch_bounds__(256) void proj_kernel(
    const float* __restrict__ x,
    const float* __restrict__ w_theta, const float* __restrict__ b_theta,
    const float* __restrict__ w_phi,   const float* __restrict__ b_phi,
    const float* __restrict__ w_g,     const float* __restrict__ b_g,
    unsigned short* __restrict__ thetaB,
    unsigned short* __restrict__ phiB32,
    unsigned short* __restrict__ gTp)
{
    __shared__ __align__(16) float x_l[64 * 132];   // [c][px] stride 132
    __shared__ float pool_l[128][41];               // 0..7 phi, 8..39 g

    const int tid = threadIdx.x;
    const int b   = blockIdx.y;
    const int rp  = blockIdx.x;          // row pair 0..31
    const int n0  = rp * 128;

    // stage x tile: 64 ch x 128 px, coalesced float4
    {
        const float4* src = (const float4*)(x + (size_t)b * C_ * HW_ + n0);
        #pragma unroll
        for (int j = 0; j < 8; j++) {
            int idx = tid + j * 256;
            int c = idx >> 5, p4 = idx & 31;
            float4 v = src[(size_t)c * (HW_ / 4) + p4];
            *(float4*)&x_l[c * 132 + p4 * 4] = v;
        }
    }
    __syncthreads();

    const int px = tid & 127;
    const int og = tid >> 7;             // wave-uniform half

    if (og == 0) {
        float th[8], ph[8], g0[8];
        #pragma unroll
        for (int o = 0; o < 8; o++) { th[o] = b_theta[o]; ph[o] = b_phi[o]; g0[o] = b_g[o]; }
        #pragma unroll 4
        for (int c = 0; c < C_; c++) {
            float xv = x_l[c * 132 + px];
            #pragma unroll
            for (int o = 0; o < 8; o++) th[o] += xv * w_theta[o * 64 + c];
            #pragma unroll
            for (int o = 0; o < 8; o++) ph[o] += xv * w_phi[o * 64 + c];
            #pragma unroll
            for (int o = 0; o < 8; o++) g0[o] += xv * w_g[o * 64 + c];
        }
        unsigned short* tout = thetaB + ((size_t)b * HW_ + n0 + px) * 8;
        uint4 tv;
        tv.x = pack2(th[0], th[1]); tv.y = pack2(th[2], th[3]);
        tv.z = pack2(th[4], th[5]); tv.w = pack2(th[6], th[7]);
        *(uint4*)tout = tv;
        #pragma unroll
        for (int o = 0; o < 8; o++) { pool_l[px][o] = ph[o]; pool_l[px][8 + o] = g0[o]; }
    } else {
        float gg[24];
        #pragma unroll
        for (int o = 0; o < 24; o++) gg[o] = b_g[8 + o];
        #pragma unroll 4
        for (int c = 0; c < C_; c++) {
            float xv = x_l[c * 132 + px];
            #pragma unroll
            for (int o = 0; o < 24; o++) gg[o] += xv * w_g[(8 + o) * 64 + c];
        }
        #pragma unroll
        for (int o = 0; o < 24; o++) pool_l[px][16 + o] = gg[o];
    }
    __syncthreads();

    // 2x2 max-pool: pooled row rp, pooled cols 0..31
    if (tid < 32) {
        const int pc  = tid;
        const int p00 = 2 * pc, p01 = 2 * pc + 1, p10 = 64 + 2 * pc, p11 = 65 + 2 * pc;
        const int mq  = rp * 32 + pc;
        float o8[8];
        #pragma unroll
        for (int o = 0; o < 8; o++)
            o8[o] = fmaxf(fmaxf(pool_l[p00][o], pool_l[p01][o]),
                          fmaxf(pool_l[p10][o], pool_l[p11][o]));
        unsigned short* pout = phiB32 + ((size_t)b * M_ + mq) * 32;
        uint4 pv;
        pv.x = pack2(o8[0], o8[1]); pv.y = pack2(o8[2], o8[3]);
        pv.z = pack2(o8[4], o8[5]); pv.w = pack2(o8[6], o8[7]);
        ((uint4*)pout)[0] = pv;
        ((uint4*)pout)[1] = make_uint4(0, 0, 0, 0);   // k-pad 8..15
        ((uint4*)pout)[2] = make_uint4(0, 0, 0, 0);   // 16..23
        ((uint4*)pout)[3] = make_uint4(0, 0, 0, 0);   // 24..31
    } else if (tid < 64) {
        const int j   = tid - 32;        // pooled col = m & 31
        const int p00 = 2 * j, p01 = 2 * j + 1, p10 = 64 + 2 * j, p11 = 65 + 2 * j;
        // permuted column: p = rp*32 + ((j>>2)&3)*8 + (j>>4)*4 + (j&3)
        const int pcol = rp * 32 + ((j >> 2) & 3) * 8 + (j >> 4) * 4 + (j & 3);
        unsigned short* gout = gTp + (size_t)b * 32 * M_ + pcol;
        #pragma unroll
        for (int c = 0; c < 32; c++) {
            const int s = c + 8;
            float v = fmaxf(fmaxf(pool_l[p00][s], pool_l[p01][s]),
                            fmaxf(pool_l[p10][s], pool_l[p11][s]));
            gout[(size_t)c * M_] = f2bf(v);
        }
    }
}

// ---------------------------------------------------------------------------
// attn: block = (batch, 64-q tile), 256 thr = 4 waves; wave wv owns q rows
// wv*16..+15 and is fully independent until the epilogue. Per 64-m chunk:
// 4 score MFMAs (S^T = phi.theta^T) -> 16 exp -> pack -> 4 PV MFMAs, all
// operands global->register (prefetch-rotated). No LDS in the loop.
// ---------------------------------------------------------------------------
__global__ __launch_bounds__(256) void attn_kernel(
    const float* __restrict__ x,
    const unsigned short* __restrict__ thetaB,   // [b][n][8]
    const unsigned short* __restrict__ phiB32,   // [b][m][32], cols 8..31 = 0
    const unsigned short* __restrict__ gTp,      // [b][c][1024] permuted
    const float* __restrict__ w_o, const float* __restrict__ b_o,
    const float* __restrict__ sigma,
    float* __restrict__ out)
{
    __shared__ float O_l[64 * 33];
    __shared__ float rs_l[64];

    const int tid   = threadIdx.x;
    const int b     = blockIdx.y;
    const int qbase = blockIdx.x * 64;
    const int wv    = tid >> 6;
    const int lane  = tid & 63;
    const int ln15  = lane & 15;
    const int quad  = lane >> 4;

    const unsigned short* phiP = phiB32 + (size_t)b * M_ * 32;
    const unsigned short* gP   = gTp    + (size_t)b * 32 * M_;

    // theta B-fragment, once: lane (q=ln15) quad 0 holds theta[q][0..7];
    // quads 1..3 are the k-pad -> zero (single cndmask).
    bf16x8 tfrag;
    {
        const unsigned short* tp =
            thetaB + ((size_t)b * HW_ + qbase + wv * 16 + ln15) * 8;
        bf16x8 t = *(const bf16x8*)tp;
        bf16x8 z = {0, 0, 0, 0, 0, 0, 0, 0};
        tfrag = (quad == 0) ? t : z;
    }

    // per-chunk loads (all 16B, L1/L2-hot after first touch)
    #define LD_PHI(ch_, t_) \
        (*(const bf16x8*)(phiP + ((size_t)((ch_) * 64 + (t_) * 16 + ln15)) * 32 + quad * 8))
    #define LD_G(ch_, h_, s_) \
        (*(const bf16x8*)(gP + (size_t)((h_) * 16 + ln15) * M_ + (ch_) * 64 + (s_) * 32 + quad * 8))

    f32x4 acc0 = {0.f, 0.f, 0.f, 0.f};   // O^T rows c=0..15 (c-local=quad*4+r), col q=ln15
    f32x4 acc1 = {0.f, 0.f, 0.f, 0.f};   // c=16..31
    float rs_part = 0.f;

    bf16x8 pf[4], gf[4];
    #pragma unroll
    for (int t = 0; t < 4; t++) pf[t] = LD_PHI(0, t);
    gf[0] = LD_G(0, 0, 0); gf[1] = LD_G(0, 0, 1);
    gf[2] = LD_G(0, 1, 0); gf[3] = LD_G(0, 1, 1);

    for (int ch = 0; ch < 16; ch++) {
        const int nc = (ch < 15) ? ch + 1 : 15;
        bf16x8 npf[4], ngf[4];
        #pragma unroll
        for (int t = 0; t < 4; t++) npf[t] = LD_PHI(nc, t);
        ngf[0] = LD_G(nc, 0, 0); ngf[1] = LD_G(nc, 0, 1);
        ngf[2] = LD_G(nc, 1, 0); ngf[3] = LD_G(nc, 1, 1);

        // scores: S^T[m][q], 4 MFMAs (A=phi rows m=t*16+ln15, B=theta)
        const f32x4 zc = {0.f, 0.f, 0.f, 0.f};
        f32x4 S0 = __builtin_amdgcn_mfma_f32_16x16x32_bf16(pf[0], tfrag, zc, 0, 0, 0);
        f32x4 S1 = __builtin_amdgcn_mfma_f32_16x16x32_bf16(pf[1], tfrag, zc, 0, 0, 0);
        f32x4 S2 = __builtin_amdgcn_mfma_f32_16x16x32_bf16(pf[2], tfrag, zc, 0, 0, 0);
        f32x4 S3 = __builtin_amdgcn_mfma_f32_16x16x32_bf16(pf[3], tfrag, zc, 0, 0, 0);

        // exp + rowsum partial + pack P as PV B-fragments (register-resident).
        // sub s uses S_{2s} (j=0..3) and S_{2s+1} (j=4..7):
        // k=quad*8+j <-> m = s*32 + (j>>2)*16 + quad*4 + (j&3).
        union { bf16x8 v; unsigned int u[4]; } pb0, pb1;
        {
            float e0[4], e1[4], e2[4], e3[4];
            #pragma unroll
            for (int r = 0; r < 4; r++) {
                e0[r] = __expf(fminf(S0[r], 80.f));
                e1[r] = __expf(fminf(S1[r], 80.f));
                e2[r] = __expf(fminf(S2[r], 80.f));
                e3[r] = __expf(fminf(S3[r], 80.f));
                rs_part += e0[r] + e1[r] + e2[r] + e3[r];
            }
            pb0.u[0] = pack2(e0[0], e0[1]); pb0.u[1] = pack2(e0[2], e0[3]);
            pb0.u[2] = pack2(e1[0], e1[1]); pb0.u[3] = pack2(e1[2], e1[3]);
            pb1.u[0] = pack2(e2[0], e2[1]); pb1.u[1] = pack2(e2[2], e2[3]);
            pb1.u[2] = pack2(e3[0], e3[1]); pb1.u[3] = pack2(e3[2], e3[3]);
        }

        // PV: O^T[c][q] += gT[c][m] P^T[m][q]
        acc0 = __builtin_amdgcn_mfma_f32_16x16x32_bf16(gf[0], pb0.v, acc0, 0, 0, 0);
        acc0 = __builtin_amdgcn_mfma_f32_16x16x32_bf16(gf[1], pb1.v, acc0, 0, 0, 0);
        acc1 = __builtin_amdgcn_mfma_f32_16x16x32_bf16(gf[2], pb0.v, acc1, 0, 0, 0);
        acc1 = __builtin_amdgcn_mfma_f32_16x16x32_bf16(gf[3], pb1.v, acc1, 0, 0, 0);

        #pragma unroll
        for (int t = 0; t < 4; t++) { pf[t] = npf[t]; gf[t] = ngf[t]; }
    }
    #undef LD_PHI
    #undef LD_G

    // rowsum for q=ln15: sum lane partials across quads
    {
        float v = rs_part;
        v += __shfl_xor(v, 16);
        v += __shfl_xor(v, 32);
        if (quad == 0) rs_l[wv * 16 + ln15] = v;
    }
    // O^T -> O_l[q][c]: lane writes col q=ln15, rows c = half*16 + quad*4 + r
    {
        const int q = wv * 16 + ln15;
        #pragma unroll
        for (int r = 0; r < 4; r++) {
            O_l[q * 33 + quad * 4 + r]      = acc0[r];
            O_l[q * 33 + 16 + quad * 4 + r] = acc1[r];
        }
    }
    __syncthreads();

    // epilogue: normalize + w_o conv + bias + residual
    const int q = tid & 63;
    const float rowsum = rs_l[q];
    const float sg  = sigma[0];
    const float inv = sg / rowsum;
    float o[32];
    #pragma unroll
    for (int c = 0; c < 32; c++) o[c] = O_l[q * 33 + c];
    const size_t xb = (size_t)b * C_ * HW_ + qbase + q;
    #pragma unroll
    for (int k = 0; k < 16; k++) {
        const int co = wv * 16 + k;
        float t = 0.f;
        #pragma unroll
        for (int c = 0; c < 32; c++) t += w_o[co * 32 + c] * o[c];
        out[xb + (size_t)co * HW_] = x[xb + (size_t)co * HW_] + t * inv + sg * b_o[co];
    }
}

// ---------------------------------------------------------------------------
extern "C" void kernel_launch(void* const* d_in, const int* in_sizes, int n_in,
                              void* d_out, int out_size, void* d_ws, size_t ws_size,
                              hipStream_t stream)
{
    const float* x       = (const float*)d_in[0];
    const float* w_theta = (const float*)d_in[1];
    const float* b_theta = (const float*)d_in[2];
    const float* w_phi   = (const float*)d_in[3];
    const float* b_phi   = (const float*)d_in[4];
    const float* w_g     = (const float*)d_in[5];
    const float* b_g     = (const float*)d_in[6];
    const float* w_o     = (const float*)d_in[7];
    const float* b_o     = (const float*)d_in[8];
    const float* sigma   = (const float*)d_in[9];
    float* out = (float*)d_out;

    // workspace (bf16): theta 1 MB, phi32 1 MB, gTp 1 MB
    unsigned short* thetaB = (unsigned short*)d_ws;
    unsigned short* phiB32 = thetaB + (size_t)B_ * HW_ * 8;
    unsigned short* gTp    = phiB32 + (size_t)B_ * M_ * 32;

    proj_kernel<<<dim3(32, B_), 256, 0, stream>>>(
        x, w_theta, b_theta, w_phi, b_phi, w_g, b_g, thetaB, phiB32, gTp);
    attn_kernel<<<dim3(64, B_), 256, 0, stream>>>(
        x, thetaB, phiB32, gTp, w_o, b_o, sigma, out);
}

// Round 7
// 134.436 us; speedup vs baseline: 1.2064x; 1.1849x over previous
//
#include <hip/hip_runtime.h>

// Self-attention (SAGAN-style), B=16, C=64, H=W=64. d8=8, d2=32, N=4096, M=1024.
// Round 7: wave-owns-chunk attention. Each wave computes the FULL 64-q tile
// against its private 256 m (4 chunks of 64): the 8 global b128 loads per
// chunk (4 phi A-frags + 4 g A-frags) are each reused across 4 q-tiles ->
// 32 MFMAs + 64 exp per chunk per wave, latency hidden by 1-deep prefetch.
// Round-6 register P remap kept verbatim (S^T C/D layout == PV B-frag k-map:
// k=quad*8+j <-> m = s*32 + (j>>2)*16 + quad*4 + (j&3)). No LDS in the main
// loop; O/rowsum are per-wave partials over m, reduced cross-wave in the
// epilogue via LDS. proj unchanged from round 6.

#define B_   16
#define C_   64
#define HW_  4096
#define M_   1024

typedef __attribute__((ext_vector_type(8))) short bf16x8;
typedef __attribute__((ext_vector_type(4))) float f32x4;

__device__ __forceinline__ unsigned short f2bf(float f) {   // RNE
    union { float f; unsigned int u; } v; v.f = f;
    return (unsigned short)((v.u + 0x7FFFu + ((v.u >> 16) & 1u)) >> 16);
}
__device__ __forceinline__ unsigned int pack2(float a, float b) {
    return (unsigned int)f2bf(a) | ((unsigned int)f2bf(b) << 16);
}

// ---------------------------------------------------------------------------
// proj: thetaB(B,N,8) bf16 compact; phiB32(B,1024,32) bf16 with cols 8..31=0;
// gTp(B,32,1024) bf16 with m permuted per 32-block: for m, ms=m&31,
// p = (m&~31) + ((ms>>2)&3)*8 + (ms>>4)*4 + (ms&3).
// ---------------------------------------------------------------------------
__global__ __launch_bounds__(256) void proj_kernel(
    const float* __restrict__ x,
    const float* __restrict__ w_theta, const float* __restrict__ b_theta,
    const float* __restrict__ w_phi,   const float* __restrict__ b_phi,
    const float* __restrict__ w_g,     const float* __restrict__ b_g,
    unsigned short* __restrict__ thetaB,
    unsigned short* __restrict__ phiB32,
    unsigned short* __restrict__ gTp)
{
    __shared__ __align__(16) float x_l[64 * 132];   // [c][px] stride 132
    __shared__ float pool_l[128][41];               // 0..7 phi, 8..39 g

    const int tid = threadIdx.x;
    const int b   = blockIdx.y;
    const int rp  = blockIdx.x;          // row pair 0..31
    const int n0  = rp * 128;

    // stage x tile: 64 ch x 128 px, coalesced float4
    {
        const float4* src = (const float4*)(x + (size_t)b * C_ * HW_ + n0);
        #pragma unroll
        for (int j = 0; j < 8; j++) {
            int idx = tid + j * 256;
            int c = idx >> 5, p4 = idx & 31;
            float4 v = src[(size_t)c * (HW_ / 4) + p4];
            *(float4*)&x_l[c * 132 + p4 * 4] = v;
        }
    }
    __syncthreads();

    const int px = tid & 127;
    const int og = tid >> 7;             // wave-uniform half

    if (og == 0) {
        float th[8], ph[8], g0[8];
        #pragma unroll
        for (int o = 0; o < 8; o++) { th[o] = b_theta[o]; ph[o] = b_phi[o]; g0[o] = b_g[o]; }
        #pragma unroll 4
        for (int c = 0; c < C_; c++) {
            float xv = x_l[c * 132 + px];
            #pragma unroll
            for (int o = 0; o < 8; o++) th[o] += xv * w_theta[o * 64 + c];
            #pragma unroll
            for (int o = 0; o < 8; o++) ph[o] += xv * w_phi[o * 64 + c];
            #pragma unroll
            for (int o = 0; o < 8; o++) g0[o] += xv * w_g[o * 64 + c];
        }
        unsigned short* tout = thetaB + ((size_t)b * HW_ + n0 + px) * 8;
        uint4 tv;
        tv.x = pack2(th[0], th[1]); tv.y = pack2(th[2], th[3]);
        tv.z = pack2(th[4], th[5]); tv.w = pack2(th[6], th[7]);
        *(uint4*)tout = tv;
        #pragma unroll
        for (int o = 0; o < 8; o++) { pool_l[px][o] = ph[o]; pool_l[px][8 + o] = g0[o]; }
    } else {
        float gg[24];
        #pragma unroll
        for (int o = 0; o < 24; o++) gg[o] = b_g[8 + o];
        #pragma unroll 4
        for (int c = 0; c < C_; c++) {
            float xv = x_l[c * 132 + px];
            #pragma unroll
            for (int o = 0; o < 24; o++) gg[o] += xv * w_g[(8 + o) * 64 + c];
        }
        #pragma unroll
        for (int o = 0; o < 24; o++) pool_l[px][16 + o] = gg[o];
    }
    __syncthreads();

    // 2x2 max-pool: pooled row rp, pooled cols 0..31
    if (tid < 32) {
        const int pc  = tid;
        const int p00 = 2 * pc, p01 = 2 * pc + 1, p10 = 64 + 2 * pc, p11 = 65 + 2 * pc;
        const int mq  = rp * 32 + pc;
        float o8[8];
        #pragma unroll
        for (int o = 0; o < 8; o++)
            o8[o] = fmaxf(fmaxf(pool_l[p00][o], pool_l[p01][o]),
                          fmaxf(pool_l[p10][o], pool_l[p11][o]));
        unsigned short* pout = phiB32 + ((size_t)b * M_ + mq) * 32;
        uint4 pv;
        pv.x = pack2(o8[0], o8[1]); pv.y = pack2(o8[2], o8[3]);
        pv.z = pack2(o8[4], o8[5]); pv.w = pack2(o8[6], o8[7]);
        ((uint4*)pout)[0] = pv;
        ((uint4*)pout)[1] = make_uint4(0, 0, 0, 0);   // k-pad 8..15
        ((uint4*)pout)[2] = make_uint4(0, 0, 0, 0);   // 16..23
        ((uint4*)pout)[3] = make_uint4(0, 0, 0, 0);   // 24..31
    } else if (tid < 64) {
        const int j   = tid - 32;        // pooled col = m & 31
        const int p00 = 2 * j, p01 = 2 * j + 1, p10 = 64 + 2 * j, p11 = 65 + 2 * j;
        const int pcol = rp * 32 + ((j >> 2) & 3) * 8 + (j >> 4) * 4 + (j & 3);
        unsigned short* gout = gTp + (size_t)b * 32 * M_ + pcol;
        #pragma unroll
        for (int c = 0; c < 32; c++) {
            const int s = c + 8;
            float v = fmaxf(fmaxf(pool_l[p00][s], pool_l[p01][s]),
                            fmaxf(pool_l[p10][s], pool_l[p11][s]));
            gout[(size_t)c * M_] = f2bf(v);
        }
    }
}

// ---------------------------------------------------------------------------
// attn: block = (batch, 64-q tile), 256 thr = 4 waves. Wave wv privately owns
// m-chunks wv*4 .. wv*4+3 (256 m) and computes ALL 64 q against them:
// per chunk: 8 global b128 loads (reused 4x), 16 score MFMAs + 16 PV MFMAs,
// 64 exp. Partial O^T / rowsum per wave; cross-wave reduce in epilogue.
// ---------------------------------------------------------------------------
__global__ __launch_bounds__(256) void attn_kernel(
    const float* __restrict__ x,
    const unsigned short* __restrict__ thetaB,   // [b][n][8]
    const unsigned short* __restrict__ phiB32,   // [b][m][32], cols 8..31 = 0
    const unsigned short* __restrict__ gTp,      // [b][c][1024] m-permuted
    const float* __restrict__ w_o, const float* __restrict__ b_o,
    const float* __restrict__ sigma,
    float* __restrict__ out)
{
    __shared__ float Op_l[4][64 * 33];   // [wv][q][c] partial O, 33.8 KB
    __shared__ float rs_l[4][64];        // [wv][q] partial rowsums

    const int tid   = threadIdx.x;
    const int b     = blockIdx.y;
    const int qbase = blockIdx.x * 64;
    const int wv    = tid >> 6;
    const int lane  = tid & 63;
    const int ln15  = lane & 15;
    const int quad  = lane >> 4;

    const unsigned short* phiP = phiB32 + (size_t)b * M_ * 32;
    const unsigned short* gP   = gTp    + (size_t)b * 32 * M_;

    // theta B-frags for the 4 q-tiles (loaded once; quad 0 real, rest zero)
    bf16x8 th[4];
    {
        const bf16x8 z = {0, 0, 0, 0, 0, 0, 0, 0};
        #pragma unroll
        for (int qt = 0; qt < 4; qt++) {
            const unsigned short* tp =
                thetaB + ((size_t)b * HW_ + qbase + qt * 16 + ln15) * 8;
            bf16x8 t = *(const bf16x8*)tp;
            th[qt] = (quad == 0) ? t : z;
        }
    }

    #define LD_PHI(ch_, mt_) \
        (*(const bf16x8*)(phiP + ((size_t)((ch_) * 64 + (mt_) * 16 + ln15)) * 32 + quad * 8))
    #define LD_G(ch_, h_, s_) \
        (*(const bf16x8*)(gP + (size_t)((h_) * 16 + ln15) * M_ + (ch_) * 64 + (s_) * 32 + quad * 8))

    f32x4 acc[2][4];                     // [c-half][q-tile], O^T partial
    #pragma unroll
    for (int h = 0; h < 2; h++)
        #pragma unroll
        for (int qt = 0; qt < 4; qt++) acc[h][qt] = (f32x4){0.f, 0.f, 0.f, 0.f};
    float rs_p[4] = {0.f, 0.f, 0.f, 0.f};

    bf16x8 pf[4], gf[2][2];
    {
        const int ch = wv * 4;
        #pragma unroll
        for (int mt = 0; mt < 4; mt++) pf[mt] = LD_PHI(ch, mt);
        gf[0][0] = LD_G(ch, 0, 0); gf[0][1] = LD_G(ch, 0, 1);
        gf[1][0] = LD_G(ch, 1, 0); gf[1][1] = LD_G(ch, 1, 1);
    }

    for (int wc = 0; wc < 4; wc++) {
        const int nch = wv * 4 + ((wc < 3) ? wc + 1 : 3);
        bf16x8 npf[4], ngf[2][2];
        #pragma unroll
        for (int mt = 0; mt < 4; mt++) npf[mt] = LD_PHI(nch, mt);
        ngf[0][0] = LD_G(nch, 0, 0); ngf[0][1] = LD_G(nch, 0, 1);
        ngf[1][0] = LD_G(nch, 1, 0); ngf[1][1] = LD_G(nch, 1, 1);

        #pragma unroll
        for (int s = 0; s < 2; s++) {
            #pragma unroll
            for (int qt = 0; qt < 4; qt++) {
                const f32x4 zc = {0.f, 0.f, 0.f, 0.f};
                f32x4 S0 = __builtin_amdgcn_mfma_f32_16x16x32_bf16(pf[2 * s],     th[qt], zc, 0, 0, 0);
                f32x4 S1 = __builtin_amdgcn_mfma_f32_16x16x32_bf16(pf[2 * s + 1], th[qt], zc, 0, 0, 0);
                float e0[4], e1[4];
                #pragma unroll
                for (int r = 0; r < 4; r++) {
                    e0[r] = __expf(S0[r]);
                    e1[r] = __expf(S1[r]);
                    rs_p[qt] += e0[r] + e1[r];
                }
                union { bf16x8 v; unsigned int u[4]; } pb;
                pb.u[0] = pack2(e0[0], e0[1]); pb.u[1] = pack2(e0[2], e0[3]);
                pb.u[2] = pack2(e1[0], e1[1]); pb.u[3] = pack2(e1[2], e1[3]);
                acc[0][qt] = __builtin_amdgcn_mfma_f32_16x16x32_bf16(gf[0][s], pb.v, acc[0][qt], 0, 0, 0);
                acc[1][qt] = __builtin_amdgcn_mfma_f32_16x16x32_bf16(gf[1][s], pb.v, acc[1][qt], 0, 0, 0);
            }
        }

        #pragma unroll
        for (int mt = 0; mt < 4; mt++) pf[mt] = npf[mt];
        gf[0][0] = ngf[0][0]; gf[0][1] = ngf[0][1];
        gf[1][0] = ngf[1][0]; gf[1][1] = ngf[1][1];
    }
    #undef LD_PHI
    #undef LD_G

    // rowsum partials: reduce over quads (m-rows) within the wave
    {
        float v[4];
        #pragma unroll
        for (int qt = 0; qt < 4; qt++) {
            float t = rs_p[qt];
            t += __shfl_xor(t, 16);
            t += __shfl_xor(t, 32);
            v[qt] = t;
        }
        if (quad == 0) {
            #pragma unroll
            for (int qt = 0; qt < 4; qt++) rs_l[wv][qt * 16 + ln15] = v[qt];
        }
    }
    // O^T partials -> LDS: lane owns col q=qt*16+ln15, rows c=h*16+quad*4+r
    #pragma unroll
    for (int h = 0; h < 2; h++)
        #pragma unroll
        for (int qt = 0; qt < 4; qt++)
            #pragma unroll
            for (int r = 0; r < 4; r++)
                Op_l[wv][(qt * 16 + ln15) * 33 + h * 16 + quad * 4 + r] = acc[h][qt][r];
    __syncthreads();

    // epilogue: cross-wave reduce + normalize + w_o conv + bias + residual
    const int q = tid & 63;
    const float rowsum = rs_l[0][q] + rs_l[1][q] + rs_l[2][q] + rs_l[3][q];
    const float sg  = sigma[0];
    const float inv = sg / rowsum;
    float o[32];
    #pragma unroll
    for (int c = 0; c < 32; c++)
        o[c] = Op_l[0][q * 33 + c] + Op_l[1][q * 33 + c]
             + Op_l[2][q * 33 + c] + Op_l[3][q * 33 + c];
    const size_t xb = (size_t)b * C_ * HW_ + qbase + q;
    #pragma unroll
    for (int k = 0; k < 16; k++) {
        const int co = wv * 16 + k;
        float t = 0.f;
        #pragma unroll
        for (int c = 0; c < 32; c++) t += w_o[co * 32 + c] * o[c];
        out[xb + (size_t)co * HW_] = x[xb + (size_t)co * HW_] + t * inv + sg * b_o[co];
    }
}

// ---------------------------------------------------------------------------
extern "C" void kernel_launch(void* const* d_in, const int* in_sizes, int n_in,
                              void* d_out, int out_size, void* d_ws, size_t ws_size,
                              hipStream_t stream)
{
    const float* x       = (const float*)d_in[0];
    const float* w_theta = (const float*)d_in[1];
    const float* b_theta = (const float*)d_in[2];
    const float* w_phi   = (const float*)d_in[3];
    const float* b_phi   = (const float*)d_in[4];
    const float* w_g     = (const float*)d_in[5];
    const float* b_g     = (const float*)d_in[6];
    const float* w_o     = (const float*)d_in[7];
    const float* b_o     = (const float*)d_in[8];
    const float* sigma   = (const float*)d_in[9];
    float* out = (float*)d_out;

    // workspace (bf16): theta 1 MB, phi32 1 MB, gTp 1 MB
    unsigned short* thetaB = (unsigned short*)d_ws;
    unsigned short* phiB32 = thetaB + (size_t)B_ * HW_ * 8;
    unsigned short* gTp    = phiB32 + (size_t)B_ * M_ * 32;

    proj_kernel<<<dim3(32, B_), 256, 0, stream>>>(
        x, w_theta, b_theta, w_phi, b_phi, w_g, b_g, thetaB, phiB32, gTp);
    attn_kernel<<<dim3(64, B_), 256, 0, stream>>>(
        x, thetaB, phiB32, gTp, w_o, b_o, sigma, out);
}

// Round 8
// 126.800 us; speedup vs baseline: 1.2791x; 1.0602x over previous
//
#include <hip/hip_runtime.h>

// Self-attention (SAGAN-style), B=16, C=64, H=W=64. d8=8, d2=32, N=4096, M=1024.
// Round 8: (a) attn: drop explicit prefetch double-buffer (unrolled loop +
// compiler vmcnt pipelining within a 128-VGPR budget), __launch_bounds__(256,4)
// to pin 4 waves/SIMD, truncation pack for P (3 VALU vs ~10; P>0, bias tiny).
// (b) proj: pooling tail parallelized across all 256 threads (was 1 wave doing
// ~160 serial LDS reads + 1024 scattered 2B stores); phi pads zeroed block-
// parallel. Math/layouts identical to round 7 (passed, absmax 0.0156).

#define B_   16
#define C_   64
#define HW_  4096
#define M_   1024

typedef __attribute__((ext_vector_type(8))) short bf16x8;
typedef __attribute__((ext_vector_type(4))) float f32x4;

__device__ __forceinline__ unsigned short f2bf(float f) {   // RNE
    union { float f; unsigned int u; } v; v.f = f;
    return (unsigned short)((v.u + 0x7FFFu + ((v.u >> 16) & 1u)) >> 16);
}
__device__ __forceinline__ unsigned int pack2(float a, float b) {   // RNE pair
    return (unsigned int)f2bf(a) | ((unsigned int)f2bf(b) << 16);
}
__device__ __forceinline__ unsigned int pack2t(float a, float b) {  // trunc pair
    union { float f; unsigned int u; } ua, ub; ua.f = a; ub.f = b;
    return (ua.u >> 16) | (ub.u & 0xFFFF0000u);
}

// ---------------------------------------------------------------------------
// proj: thetaB(B,N,8) bf16 compact; phiB32(B,1024,32) bf16 with cols 8..31=0;
// gTp(B,32,1024) bf16 with m permuted per 32-block: ms=m&31,
// p = (m&~31) + ((ms>>2)&3)*8 + (ms>>4)*4 + (ms&3).
// ---------------------------------------------------------------------------
__global__ __launch_bounds__(256) void proj_kernel(
    const float* __restrict__ x,
    const float* __restrict__ w_theta, const float* __restrict__ b_theta,
    const float* __restrict__ w_phi,   const float* __restrict__ b_phi,
    const float* __restrict__ w_g,     const float* __restrict__ b_g,
    unsigned short* __restrict__ thetaB,
    unsigned short* __restrict__ phiB32,
    unsigned short* __restrict__ gTp)
{
    __shared__ __align__(16) float x_l[64 * 132];   // [c][px] stride 132
    __shared__ float pool_l[128][41];               // 0..7 phi, 8..39 g

    const int tid = threadIdx.x;
    const int b   = blockIdx.y;
    const int rp  = blockIdx.x;          // row pair 0..31
    const int n0  = rp * 128;

    // stage x tile: 64 ch x 128 px, coalesced float4
    {
        const float4* src = (const float4*)(x + (size_t)b * C_ * HW_ + n0);
        #pragma unroll
        for (int j = 0; j < 8; j++) {
            int idx = tid + j * 256;
            int c = idx >> 5, p4 = idx & 31;
            float4 v = src[(size_t)c * (HW_ / 4) + p4];
            *(float4*)&x_l[c * 132 + p4 * 4] = v;
        }
    }
    __syncthreads();

    const int px = tid & 127;
    const int og = tid >> 7;             // wave-uniform half

    if (og == 0) {
        float th[8], ph[8], g0[8];
        #pragma unroll
        for (int o = 0; o < 8; o++) { th[o] = b_theta[o]; ph[o] = b_phi[o]; g0[o] = b_g[o]; }
        #pragma unroll 4
        for (int c = 0; c < C_; c++) {
            float xv = x_l[c * 132 + px];
            #pragma unroll
            for (int o = 0; o < 8; o++) th[o] += xv * w_theta[o * 64 + c];
            #pragma unroll
            for (int o = 0; o < 8; o++) ph[o] += xv * w_phi[o * 64 + c];
            #pragma unroll
            for (int o = 0; o < 8; o++) g0[o] += xv * w_g[o * 64 + c];
        }
        unsigned short* tout = thetaB + ((size_t)b * HW_ + n0 + px) * 8;
        uint4 tv;
        tv.x = pack2(th[0], th[1]); tv.y = pack2(th[2], th[3]);
        tv.z = pack2(th[4], th[5]); tv.w = pack2(th[6], th[7]);
        *(uint4*)tout = tv;
        #pragma unroll
        for (int o = 0; o < 8; o++) { pool_l[px][o] = ph[o]; pool_l[px][8 + o] = g0[o]; }
    } else {
        float gg[24];
        #pragma unroll
        for (int o = 0; o < 24; o++) gg[o] = b_g[8 + o];
        #pragma unroll 4
        for (int c = 0; c < C_; c++) {
            float xv = x_l[c * 132 + px];
            #pragma unroll
            for (int o = 0; o < 24; o++) gg[o] += xv * w_g[(8 + o) * 64 + c];
        }
        #pragma unroll
        for (int o = 0; o < 24; o++) pool_l[px][16 + o] = gg[o];
    }
    __syncthreads();

    // parallel 2x2 max-pool over all 256 threads:
    // j = pooled col (0..31), grp = tid>>5 (0..7) handles channels grp*5..grp*5+4
    {
        const int j   = tid & 31;
        const int grp = tid >> 5;
        const int p00 = 2 * j, p01 = 2 * j + 1, p10 = 64 + 2 * j, p11 = 65 + 2 * j;
        const int mq   = rp * 32 + j;
        const int pcol = rp * 32 + ((j >> 2) & 3) * 8 + (j >> 4) * 4 + (j & 3);
        #pragma unroll
        for (int k = 0; k < 5; k++) {
            const int ch = grp * 5 + k;          // 0..39 exactly
            float v = fmaxf(fmaxf(pool_l[p00][ch], pool_l[p01][ch]),
                            fmaxf(pool_l[p10][ch], pool_l[p11][ch]));
            if (ch < 8)
                phiB32[((size_t)b * M_ + mq) * 32 + ch] = f2bf(v);
            else
                gTp[((size_t)b * 32 + (ch - 8)) * M_ + pcol] = f2bf(v);
        }
        // zero phi k-pads (cols 8..31): 32 m x 3 uint4
        if (tid < 96) {
            const int m = tid / 3, seg = tid % 3;
            *(uint4*)(phiB32 + ((size_t)b * M_ + rp * 32 + m) * 32 + 8 + seg * 8) =
                make_uint4(0, 0, 0, 0);
        }
    }
}

// ---------------------------------------------------------------------------
// attn: block = (batch, 64-q tile), 256 thr = 4 waves. Wave wv privately owns
// m-chunks wv*4..wv*4+3; per chunk: 8 global b128 loads (reused over 4
// q-tiles), 16 score + 16 PV MFMAs, 64 exp. Register P remap: S^T C-layout
// == PV B-frag with k=quad*8+j <-> m = s*32 + (j>>2)*16 + quad*4 + (j&3).
// Partial O^T / rowsum per wave; cross-wave reduce in epilogue.
// ---------------------------------------------------------------------------
__global__ __launch_bounds__(256, 4) void attn_kernel(
    const float* __restrict__ x,
    const unsigned short* __restrict__ thetaB,   // [b][n][8]
    const unsigned short* __restrict__ phiB32,   // [b][m][32], cols 8..31 = 0
    const unsigned short* __restrict__ gTp,      // [b][c][1024] m-permuted
    const float* __restrict__ w_o, const float* __restrict__ b_o,
    const float* __restrict__ sigma,
    float* __restrict__ out)
{
    __shared__ float Op_l[4][64 * 33];   // [wv][q][c] partial O
    __shared__ float rs_l[4][64];        // [wv][q] partial rowsums

    const int tid   = threadIdx.x;
    const int b     = blockIdx.y;
    const int qbase = blockIdx.x * 64;
    const int wv    = tid >> 6;
    const int lane  = tid & 63;
    const int ln15  = lane & 15;
    const int quad  = lane >> 4;

    const unsigned short* phiP = phiB32 + (size_t)b * M_ * 32;
    const unsigned short* gP   = gTp    + (size_t)b * 32 * M_;

    // theta B-frags for the 4 q-tiles (loaded once; quad 0 real, rest zero)
    bf16x8 th[4];
    {
        const bf16x8 z = {0, 0, 0, 0, 0, 0, 0, 0};
        #pragma unroll
        for (int qt = 0; qt < 4; qt++) {
            const unsigned short* tp =
                thetaB + ((size_t)b * HW_ + qbase + qt * 16 + ln15) * 8;
            bf16x8 t = *(const bf16x8*)tp;
            th[qt] = (quad == 0) ? t : z;
        }
    }

    #define LD_PHI(ch_, mt_) \
        (*(const bf16x8*)(phiP + ((size_t)((ch_) * 64 + (mt_) * 16 + ln15)) * 32 + quad * 8))
    #define LD_G(ch_, h_, s_) \
        (*(const bf16x8*)(gP + (size_t)((h_) * 16 + ln15) * M_ + (ch_) * 64 + (s_) * 32 + quad * 8))

    f32x4 acc[2][4];                     // [c-half][q-tile], O^T partial
    #pragma unroll
    for (int h = 0; h < 2; h++)
        #pragma unroll
        for (int qt = 0; qt < 4; qt++) acc[h][qt] = (f32x4){0.f, 0.f, 0.f, 0.f};
    float rs_p[4] = {0.f, 0.f, 0.f, 0.f};

    #pragma unroll
    for (int wc = 0; wc < 4; wc++) {
        const int ch = wv * 4 + wc;
        bf16x8 pf[4];
        #pragma unroll
        for (int mt = 0; mt < 4; mt++) pf[mt] = LD_PHI(ch, mt);
        bf16x8 gf[2][2];
        gf[0][0] = LD_G(ch, 0, 0); gf[0][1] = LD_G(ch, 0, 1);
        gf[1][0] = LD_G(ch, 1, 0); gf[1][1] = LD_G(ch, 1, 1);

        #pragma unroll
        for (int s = 0; s < 2; s++) {
            #pragma unroll
            for (int qt = 0; qt < 4; qt++) {
                const f32x4 zc = {0.f, 0.f, 0.f, 0.f};
                f32x4 S0 = __builtin_amdgcn_mfma_f32_16x16x32_bf16(pf[2 * s],     th[qt], zc, 0, 0, 0);
                f32x4 S1 = __builtin_amdgcn_mfma_f32_16x16x32_bf16(pf[2 * s + 1], th[qt], zc, 0, 0, 0);
                float e0[4], e1[4];
                #pragma unroll
                for (int r = 0; r < 4; r++) {
                    e0[r] = __expf(S0[r]);
                    e1[r] = __expf(S1[r]);
                    rs_p[qt] += e0[r] + e1[r];
                }
                union { bf16x8 v; unsigned int u[4]; } pb;
                pb.u[0] = pack2t(e0[0], e0[1]); pb.u[1] = pack2t(e0[2], e0[3]);
                pb.u[2] = pack2t(e1[0], e1[1]); pb.u[3] = pack2t(e1[2], e1[3]);
                acc[0][qt] = __builtin_amdgcn_mfma_f32_16x16x32_bf16(gf[0][s], pb.v, acc[0][qt], 0, 0, 0);
                acc[1][qt] = __builtin_amdgcn_mfma_f32_16x16x32_bf16(gf[1][s], pb.v, acc[1][qt], 0, 0, 0);
            }
        }
    }
    #undef LD_PHI
    #undef LD_G

    // rowsum partials: reduce over quads (m-rows) within the wave
    {
        float v[4];
        #pragma unroll
        for (int qt = 0; qt < 4; qt++) {
            float t = rs_p[qt];
            t += __shfl_xor(t, 16);
            t += __shfl_xor(t, 32);
            v[qt] = t;
        }
        if (quad == 0) {
            #pragma unroll
            for (int qt = 0; qt < 4; qt++) rs_l[wv][qt * 16 + ln15] = v[qt];
        }
    }
    // O^T partials -> LDS: lane owns col q=qt*16+ln15, rows c=h*16+quad*4+r
    #pragma unroll
    for (int h = 0; h < 2; h++)
        #pragma unroll
        for (int qt = 0; qt < 4; qt++)
            #pragma unroll
            for (int r = 0; r < 4; r++)
                Op_l[wv][(qt * 16 + ln15) * 33 + h * 16 + quad * 4 + r] = acc[h][qt][r];
    __syncthreads();

    // epilogue: cross-wave reduce + normalize + w_o conv + bias + residual
    const int q = tid & 63;
    const float rowsum = rs_l[0][q] + rs_l[1][q] + rs_l[2][q] + rs_l[3][q];
    const float sg  = sigma[0];
    const float inv = sg / rowsum;
    float o[32];
    #pragma unroll
    for (int c = 0; c < 32; c++)
        o[c] = Op_l[0][q * 33 + c] + Op_l[1][q * 33 + c]
             + Op_l[2][q * 33 + c] + Op_l[3][q * 33 + c];
    const size_t xb = (size_t)b * C_ * HW_ + qbase + q;
    #pragma unroll
    for (int k = 0; k < 16; k++) {
        const int co = wv * 16 + k;
        float t = 0.f;
        #pragma unroll
        for (int c = 0; c < 32; c++) t += w_o[co * 32 + c] * o[c];
        out[xb + (size_t)co * HW_] = x[xb + (size_t)co * HW_] + t * inv + sg * b_o[co];
    }
}

// ---------------------------------------------------------------------------
extern "C" void kernel_launch(void* const* d_in, const int* in_sizes, int n_in,
                              void* d_out, int out_size, void* d_ws, size_t ws_size,
                              hipStream_t stream)
{
    const float* x       = (const float*)d_in[0];
    const float* w_theta = (const float*)d_in[1];
    const float* b_theta = (const float*)d_in[2];
    const float* w_phi   = (const float*)d_in[3];
    const float* b_phi   = (const float*)d_in[4];
    const float* w_g     = (const float*)d_in[5];
    const float* b_g     = (const float*)d_in[6];
    const float* w_o     = (const float*)d_in[7];
    const float* b_o     = (const float*)d_in[8];
    const float* sigma   = (const float*)d_in[9];
    float* out = (float*)d_out;

    // workspace (bf16): theta 1 MB, phi32 1 MB, gTp 1 MB
    unsigned short* thetaB = (unsigned short*)d_ws;
    unsigned short* phiB32 = thetaB + (size_t)B_ * HW_ * 8;
    unsigned short* gTp    = phiB32 + (size_t)B_ * M_ * 32;

    proj_kernel<<<dim3(32, B_), 256, 0, stream>>>(
        x, w_theta, b_theta, w_phi, b_phi, w_g, b_g, thetaB, phiB32, gTp);
    attn_kernel<<<dim3(64, B_), 256, 0, stream>>>(
        x, thetaB, phiB32, gTp, w_o, b_o, sigma, out);
}